// Round 10
// baseline (266.153 us; speedup 1.0000x reference)
//
#include <hip/hip_runtime.h>
#include <cmath>

#define SEQ 2048
#define BATCH 2
#define HID 1024
#define NH 16
#define NKV 4
#define DH 64
#define KVDIM 256
#define K32C 32          // K=1024 -> 32 chunks of 32

typedef __attribute__((ext_vector_type(8))) short bf16x8;
typedef __attribute__((ext_vector_type(4))) float f32x4;

static __device__ __forceinline__ unsigned short f2bf(float x) {
  union { float f; unsigned u; } v; v.f = x;
  unsigned r = v.u + 0x7fffu + ((v.u >> 16) & 1u);  // RNE
  return (unsigned short)(r >> 16);
}
static __device__ __forceinline__ float bf2f(unsigned short h) {
  union { unsigned u; float f; } v; v.u = ((unsigned)h) << 16;
  return v.f;
}
static __device__ __forceinline__ void gl_lds16(const void* g, void* l) {
  __builtin_amdgcn_global_load_lds(
      (const __attribute__((address_space(1))) unsigned int*)g,
      (__attribute__((address_space(3))) unsigned int*)l, 16, 0, 0);
}

// fast sincos: sin/cos(sf*invf) via hardware v_sin/v_cos (revolution domain).
static __device__ __forceinline__ void fast_sincos(
    float sf, float g, float* sn, float* cs) {
  float p = sf * g;
  float pe = fmaf(sf, g, -p);          // exact rounding residual
  float rev = (p - floorf(p)) + pe;
  rev -= floorf(rev);                  // [0,1)
  *sn = __builtin_amdgcn_sinf(rev);    // sin(2*pi*rev)
  *cs = __builtin_amdgcn_cosf(rev);
}

// ---- pack bodies (device funcs shared by prep kernel and standalone) -------
template<bool HILO>
static __device__ __forceinline__ void pack_a_body(
    const float* __restrict__ A, unsigned short* __restrict__ hi,
    unsigned short* __restrict__ lo, int lbid) {
  int gid = lbid * 256 + threadIdx.x;
  int lane = gid & 63;
  int k32 = (gid >> 6) & 31;
  int m16 = gid >> 11;
  int quad = lane >> 4, l16 = lane & 15;
  const float* src = A + (size_t)(m16 * 16 + l16) * 1024 + k32 * 32 + quad * 8;
  float4 a0 = *(const float4*)src;
  float4 a1 = *(const float4*)(src + 4);
  float v[8] = {a0.x, a0.y, a0.z, a0.w, a1.x, a1.y, a1.z, a1.w};
  unsigned short h[8], l[8];
#pragma unroll
  for (int j = 0; j < 8; ++j) {
    h[j] = f2bf(v[j]);
    if (HILO) l[j] = f2bf(v[j] - bf2f(h[j]));
  }
  *(bf16x8*)(hi + (size_t)gid * 8) = *(bf16x8*)h;
  if (HILO) *(bf16x8*)(lo + (size_t)gid * 8) = *(bf16x8*)l;
}

template<bool HILO>
static __device__ __forceinline__ void pack_b_body(
    const float* __restrict__ W, unsigned short* __restrict__ hi,
    unsigned short* __restrict__ lo, int Nsrc, int lbid) {
  int gid = lbid * 256 + threadIdx.x;
  int lane = gid & 63;
  int k32 = (gid >> 6) & 31;
  int n16 = gid >> 11;
  int quad = lane >> 4, l16 = lane & 15;
  int n = n16 * 16 + l16, k = k32 * 32 + quad * 8;
  unsigned short h[8], l[8];
#pragma unroll
  for (int j = 0; j < 8; ++j) {
    float v = W[(size_t)(k + j) * Nsrc + n];
    h[j] = f2bf(v);
    if (HILO) l[j] = f2bf(v - bf2f(h[j]));
  }
  *(bf16x8*)(hi + (size_t)gid * 8) = *(bf16x8*)h;
  if (HILO) *(bf16x8*)(lo + (size_t)gid * 8) = *(bf16x8*)l;
}

// ---- standalone pack_a (used post-attention for the O-proj input) ----------
template<bool HILO>
__global__ __launch_bounds__(256) void pack_a_kernel(
    const float* __restrict__ A, unsigned short* __restrict__ hi,
    unsigned short* __restrict__ lo) {
  pack_a_body<HILO>(A, hi, lo, blockIdx.x);
}

// ---- mega prep kernel: all input packing + bias concat in ONE dispatch -----
__global__ __launch_bounds__(256) void prep_pack_kernel(
    const float* __restrict__ hs, const float* __restrict__ Wq,
    const float* __restrict__ Wk, const float* __restrict__ Wv,
    const float* __restrict__ Wo, const float* __restrict__ bq,
    const float* __restrict__ bk, const float* __restrict__ bv,
    unsigned short* __restrict__ hs_pk, unsigned short* __restrict__ Wqkv_hi,
    unsigned short* __restrict__ Wo_hi, unsigned short* __restrict__ Wo_lo,
    float* __restrict__ bias_c) {
  const int bid = blockIdx.x;
  if (bid < 2048) {
    pack_a_body<false>(hs, hs_pk, nullptr, bid);
  } else if (bid < 2560) {
    pack_b_body<false>(Wq, Wqkv_hi, nullptr, 1024, bid - 2048);
  } else if (bid < 2688) {
    pack_b_body<false>(Wk, Wqkv_hi + (size_t)64 * 2048 * 8, nullptr, 256, bid - 2560);
  } else if (bid < 2816) {
    pack_b_body<false>(Wv, Wqkv_hi + (size_t)80 * 2048 * 8, nullptr, 256, bid - 2688);
  } else if (bid < 3328) {
    pack_b_body<true>(Wo, Wo_hi, Wo_lo, 1024, bid - 2816);
  } else {
    int n = (bid - 3328) * 256 + threadIdx.x;
    if (n < 1536)
      bias_c[n] = (n < 1024) ? bq[n] : (n < 1280 ? bk[n - 1024] : bv[n - 1280]);
  }
}

// ---- packed-input MFMA GEMM, 64x128 tile, 2-barrier (round-4 best) --------
template<int CHAINS, bool OUTBF16>
__global__ __launch_bounds__(256) void gemm_pk_kernel(
    const unsigned short* __restrict__ Ah, const unsigned short* __restrict__ Al,
    const unsigned short* __restrict__ Bh, const unsigned short* __restrict__ Bl,
    const float* __restrict__ bias, void* __restrict__ Cout, int N) {
  constexpr int NCH = (CHAINS == 3) ? 2 : 1;
  __shared__ unsigned short Asm[NCH][4 * 512];
  __shared__ unsigned short Bsm[NCH][8 * 512];
  const int tid = threadIdx.x;
  const int wave = tid >> 6, lane = tid & 63;
  const int wr = wave >> 1, wc = wave & 1;
  const int quad = lane >> 4, l16 = lane & 15;
  const size_t abase = ((size_t)(blockIdx.y * 4 + wave) * K32C) * 64 + lane;
  const size_t bbase0 = ((size_t)(blockIdx.x * 8 + wave) * K32C) * 64 + lane;
  const size_t bbase1 = ((size_t)(blockIdx.x * 8 + wave + 4) * K32C) * 64 + lane;
  f32x4 acc[2][4] = {};
  for (int k32 = 0; k32 < K32C; ++k32) {
    __syncthreads();
    gl_lds16(Ah + (abase + (size_t)k32 * 64) * 8, &Asm[0][wave * 512]);
    gl_lds16(Bh + (bbase0 + (size_t)k32 * 64) * 8, &Bsm[0][wave * 512]);
    gl_lds16(Bh + (bbase1 + (size_t)k32 * 64) * 8, &Bsm[0][(wave + 4) * 512]);
    if (CHAINS == 3) {
      gl_lds16(Al + (abase + (size_t)k32 * 64) * 8, &Asm[1][wave * 512]);
      gl_lds16(Bl + (bbase0 + (size_t)k32 * 64) * 8, &Bsm[1][wave * 512]);
      gl_lds16(Bl + (bbase1 + (size_t)k32 * 64) * 8, &Bsm[1][(wave + 4) * 512]);
    }
    __syncthreads();
    bf16x8 af[2][NCH], bfr[4][NCH];
#pragma unroll
    for (int mt = 0; mt < 2; ++mt)
#pragma unroll
      for (int ch = 0; ch < NCH; ++ch)
        af[mt][ch] = *(const bf16x8*)&Asm[ch][((wr * 2 + mt) * 64 + lane) * 8];
#pragma unroll
    for (int nt = 0; nt < 4; ++nt)
#pragma unroll
      for (int ch = 0; ch < NCH; ++ch)
        bfr[nt][ch] = *(const bf16x8*)&Bsm[ch][((wc * 4 + nt) * 64 + lane) * 8];
#pragma unroll
    for (int mt = 0; mt < 2; ++mt)
#pragma unroll
      for (int nt = 0; nt < 4; ++nt) {
        acc[mt][nt] = __builtin_amdgcn_mfma_f32_16x16x32_bf16(af[mt][0], bfr[nt][0], acc[mt][nt], 0, 0, 0);
        if (CHAINS == 3) {
          acc[mt][nt] = __builtin_amdgcn_mfma_f32_16x16x32_bf16(af[mt][1], bfr[nt][0], acc[mt][nt], 0, 0, 0);
          acc[mt][nt] = __builtin_amdgcn_mfma_f32_16x16x32_bf16(af[mt][0], bfr[nt][1], acc[mt][nt], 0, 0, 0);
        }
      }
  }
  const int n0 = blockIdx.x * 128 + wc * 64;
  const int m0 = blockIdx.y * 64 + wr * 32;
#pragma unroll
  for (int mt = 0; mt < 2; ++mt)
#pragma unroll
    for (int nt = 0; nt < 4; ++nt)
#pragma unroll
      for (int r = 0; r < 4; ++r) {
        int gm = m0 + mt * 16 + quad * 4 + r;
        int n = n0 + nt * 16 + l16;
        float v = acc[mt][nt][r] + bias[n];
        if (OUTBF16)
          ((unsigned short*)Cout)[(size_t)gm * N + n] = f2bf(v);
        else
          ((float*)Cout)[(size_t)gm * N + n] = v;
      }
}

// ---- merged RoPE+rmsnorm (fast HW trig; r9 null-but-harmless, kept) --------
__global__ __launch_bounds__(1024) void rope_norm_kernel(
    const unsigned short* __restrict__ qkv, unsigned short* __restrict__ Qh,
    unsigned short* __restrict__ Ql, unsigned short* __restrict__ Kpk,
    unsigned short* __restrict__ Vpk) {
  const int s = blockIdx.x, b = blockIdx.y;
  const int t = threadIdx.x;
  const unsigned short* row = qkv + ((size_t)b * SEQ + s) * 1536;
  const float INV2PI = 0.15915494309189535f;
  {  // ---- Q ----
    const int j = t & 511;
    float invf = __builtin_amdgcn_exp2f((float)j * (-13.287712379549449f / 512.0f));
    float c, sn;
    fast_sincos((float)s, invf * INV2PI, &sn, &c);
    float x1 = bf2f(row[j]), x2 = bf2f(row[j + 512]);
    float val = (t < 512) ? (x1 * c - x2 * sn) : (x2 * c + x1 * sn);
    float ss = val * val;
#pragma unroll
    for (int off = 1; off < 64; off <<= 1) ss += __shfl_xor(ss, off);
    float rn = rsqrtf(ss * (1.0f / 64.0f) + 1.1920929e-07f);
    float v = val * rn;
    unsigned short hi = f2bf(v);
    unsigned short lo = f2bf(v - bf2f(hi));
    int h = t >> 6, d = t & 63;
    size_t o = (size_t)(b * NH + h) * 131072 +
               ((((size_t)(s >> 4) * 2 + (d >> 5)) * 64) + ((d >> 3) & 3) * 16 + (s & 15)) * 8 + (d & 7);
    Qh[o] = hi;
    Ql[o] = lo;
  }
  if (t < 256) {  // ---- K ----
    const int j = t & 127;
    float invf = __builtin_amdgcn_exp2f((float)j * (-13.287712379549449f / 128.0f));
    float c, sn;
    fast_sincos((float)s, invf * INV2PI, &sn, &c);
    float x1 = bf2f(row[1024 + j]), x2 = bf2f(row[1024 + 128 + j]);
    float val = (t < 128) ? (x1 * c - x2 * sn) : (x2 * c + x1 * sn);
    float ss = val * val;
#pragma unroll
    for (int off = 1; off < 64; off <<= 1) ss += __shfl_xor(ss, off);
    float rn = rsqrtf(ss * (1.0f / 64.0f) + 1.1920929e-07f);
    float kv = val * rn;
    int h = t >> 6, d = t & 63;
    size_t ko = (size_t)(b * NKV + h) * 131072 +
                ((((size_t)(s >> 4) * 2 + (d >> 5)) * 64) + ((d >> 3) & 3) * 16 + (s & 15)) * 8 + (d & 7);
    Kpk[ko] = f2bf(kv);
  } else if (t < 512) {  // ---- V copy ----
    const int tv = t - 256;
    int h = tv >> 6, d = tv & 63;
    size_t vo = (size_t)(b * NKV + h) * 131072 +
                ((((size_t)(d >> 4) * 64 + (s >> 5)) * 64) + ((s >> 3) & 3) * 16 + (d & 15)) * 8 + (s & 7);
    Vpk[vo] = row[1280 + tv];
  }
}

// ------------------------- MFMA attention v9 -------------------------------
// = v6 structure with T4 counted-vmcnt (the only change):
// - mask is TRIPLE-buffered and prefetched 2 iterations ahead (2 compute
//   phases ~1100cy > ~900cy HBM latency -> fully hidden); K/V stay 1-deep
//   double-buffered (L2-hit ~200cy, one phase suffices).
// - __syncthreads -> s_waitcnt vmcnt(1) + s_barrier + sched_barrier(0).
//   vmcnt N derivation: per-wave outstanding at iter top =
//   [M(jc+1), K(jc+1), V(jc+1), M(jc+2)]; first 3 must land -> vmcnt(1).
//   Tail iter 31 (nothing newer issued) -> vmcnt(0).
//   M(jc+2) stays IN FLIGHT across the barrier — the T4 mechanism (m218).
// - buffer-reuse safety identical to v6: every slot overwrite is after a
//   barrier that follows all waves' reads of that slot (mask slot
//   (jc+2)%3 was last read at iter jc-1).
// LDS 75776 B -> still 2 blocks/CU.
__global__ __launch_bounds__(512, 4) void attn_mfma9_kernel(
    const unsigned short* __restrict__ Qh, const unsigned short* __restrict__ Ql,
    const unsigned short* __restrict__ Kpk, const unsigned short* __restrict__ Vpk,
    const float* __restrict__ mask, float* __restrict__ attn_o) {
  __shared__ __align__(16) char smem[75776];
  unsigned short* Kb = (unsigned short*)smem;            // 16384 B [2][2][2048]
  unsigned short* Vb = (unsigned short*)(smem + 16384);  // 16384 B [2][2][2048]
  float*          Msk = (float*)(smem + 32768);          // 24576 B [3][2][1024]
  unsigned short* Ps = (unsigned short*)(smem + 57344);  // 18432 B

  const int b = blockIdx.z, kvh = blockIdx.y;
  const int q0 = blockIdx.x * 32;
  const int tid = threadIdx.x, wave = tid >> 6, lane = tid & 63;
  const int jh = wave >> 2, w4 = wave & 3;
  const int quad = lane >> 4, l16 = lane & 15;
  const int h = kvh * 4 + w4;

  bf16x8 qh[2][2], ql[2][2];
  {
    const unsigned short* Qb_h = Qh + (size_t)(b * NH + h) * 131072;
    const unsigned short* Qb_l = Ql + (size_t)(b * NH + h) * 131072;
#pragma unroll
    for (int mt = 0; mt < 2; ++mt)
#pragma unroll
      for (int kf = 0; kf < 2; ++kf) {
        size_t o = ((((size_t)(q0 >> 4) + mt) * 2 + kf) * 64 + lane) * 8;
        qh[mt][kf] = *(const bf16x8*)(Qb_h + o);
        ql[mt][kf] = *(const bf16x8*)(Qb_l + o);
      }
  }

  const unsigned short* Kbase = Kpk + (size_t)(b * NKV + kvh) * 131072;
  const unsigned short* Vbase = Vpk + (size_t)(b * NKV + kvh) * 131072;

  const float* mbase = mask + ((size_t)b * SEQ + q0) * SEQ;
  const int srow = w4 * 8 + (lane >> 3);
  const int ssw = ((srow >> 2) & 1) << 4;
  const float* msrc0 = mbase + (size_t)srow * SEQ + (((lane & 7) * 4) ^ ssw);

  bf16x8 ones;
#pragma unroll
  for (int i = 0; i < 8; ++i) ones[i] = (short)0x3F80;  // bf16 1.0

  f32x4 O[2][4] = {};
  f32x4 lAcc[2] = {};

  auto stageKV = [&](int buf, int jc) {
    const int j0 = jh * (SEQ / 2) + jc * 32;
    gl_lds16(Kbase + ((((size_t)(j0 >> 4) + (w4 >> 1)) * 2 + (w4 & 1)) * 64 + lane) * 8,
             Kb + (buf * 2 + jh) * 2048 + w4 * 512);
    gl_lds16(Vbase + (((size_t)w4 * 64 + (j0 >> 5)) * 64 + lane) * 8,
             Vb + (buf * 2 + jh) * 2048 + w4 * 512);
  };
  auto stageM = [&](int slot, int jc) {
    const int j0 = jh * (SEQ / 2) + jc * 32;
    gl_lds16(msrc0 + j0, Msk + (slot * 2 + jh) * 1024 + w4 * 256);
  };

  // prologue: queue = [K0, V0, M0, M1]
  stageKV(0, 0);
  stageM(0, 0);
  stageM(1, 1);

  for (int jc = 0; jc < 32; ++jc) {
    const int cur = jc & 1;
    const int mcur = jc % 3;
    // counted drain: keep M(jc+2) in flight across the barrier
    if (jc < 31)
      asm volatile("s_waitcnt vmcnt(1)" ::: "memory");
    else
      asm volatile("s_waitcnt vmcnt(0)" ::: "memory");
    __builtin_amdgcn_s_barrier();
    __builtin_amdgcn_sched_barrier(0);

    if (jc < 31) stageKV(cur ^ 1, jc + 1);
    if (jc < 30) stageM((jc + 2) % 3, jc + 2);

    bf16x8 kbf[2][2], vbf[4];
#pragma unroll
    for (int nt = 0; nt < 2; ++nt)
#pragma unroll
      for (int kf = 0; kf < 2; ++kf)
        kbf[nt][kf] = *(const bf16x8*)&Kb[(cur * 2 + jh) * 2048 + ((nt * 2 + kf) * 64 + lane) * 8];
#pragma unroll
    for (int d16 = 0; d16 < 4; ++d16)
      vbf[d16] = *(const bf16x8*)&Vb[(cur * 2 + jh) * 2048 + (d16 * 64 + lane) * 8];

    bf16x8 pa[2];
#pragma unroll
    for (int mt = 0; mt < 2; ++mt) {
#pragma unroll
      for (int nt = 0; nt < 2; ++nt) {
        f32x4 C = {};
        C = __builtin_amdgcn_mfma_f32_16x16x32_bf16(qh[mt][0], kbf[nt][0], C, 0, 0, 0);
        C = __builtin_amdgcn_mfma_f32_16x16x32_bf16(qh[mt][1], kbf[nt][1], C, 0, 0, 0);
        C = __builtin_amdgcn_mfma_f32_16x16x32_bf16(ql[mt][0], kbf[nt][0], C, 0, 0, 0);
        C = __builtin_amdgcn_mfma_f32_16x16x32_bf16(ql[mt][1], kbf[nt][1], C, 0, 0, 0);
#pragma unroll
        for (int r = 0; r < 4; ++r) {
          int row16 = quad * 4 + r;
          float m = Msk[(mcur * 2 + jh) * 1024 + (mt * 16 + row16) * 32 +
                        ((nt * 16 + l16) ^ ((quad & 1) << 4))];
          float p = __builtin_amdgcn_exp2f(
              fmaf(C[r], 0.18033688f, fmaf(m, 1.44269504f, -11.54156033f)));
          union { float f; unsigned u; } pu; pu.f = p;
          Ps[wave * 1152 + row16 * 72 + nt * 16 + l16] =
              (unsigned short)((pu.u + 0x8000u) >> 16);
        }
      }
      pa[mt] = *(const bf16x8*)&Ps[wave * 1152 + l16 * 72 + quad * 8];
    }
#pragma unroll
    for (int mt = 0; mt < 2; ++mt) {
      lAcc[mt] = __builtin_amdgcn_mfma_f32_16x16x32_bf16(pa[mt], ones, lAcc[mt], 0, 0, 0);
#pragma unroll
      for (int nt = 0; nt < 4; ++nt)
        O[mt][nt] = __builtin_amdgcn_mfma_f32_16x16x32_bf16(pa[mt], vbf[nt], O[mt][nt], 0, 0, 0);
    }
  }

  // ---- epilogue: combine jh halves via LDS, normalize, plain stores ----
  __syncthreads();  // all loop loads drained (iter 31 waited vmcnt(0))
  float* Oex = (float*)smem;             // [4][32][68] = 34816 B
  float* lex = (float*)(smem + 34816);   // [128] floats
  if (jh == 1) {
#pragma unroll
    for (int mt = 0; mt < 2; ++mt)
#pragma unroll
      for (int r = 0; r < 4; ++r) {
        int row = mt * 16 + quad * 4 + r;
#pragma unroll
        for (int nt = 0; nt < 4; ++nt)
          Oex[((size_t)w4 * 32 + row) * 68 + nt * 16 + l16] = O[mt][nt][r];
        if (l16 == 0) lex[w4 * 32 + row] = lAcc[mt][r];
      }
  }
  __syncthreads();
  if (jh == 0) {
    float* po = attn_o + ((size_t)b * SEQ + q0) * HID + h * DH;
#pragma unroll
    for (int mt = 0; mt < 2; ++mt)
#pragma unroll
      for (int r = 0; r < 4; ++r) {
        int row = mt * 16 + quad * 4 + r;
        float inv = 1.0f / (lAcc[mt][r] + lex[w4 * 32 + row]);
#pragma unroll
        for (int nt = 0; nt < 4; ++nt) {
          float v = (O[mt][nt][r] + Oex[((size_t)w4 * 32 + row) * 68 + nt * 16 + l16]) * inv;
          po[(size_t)row * HID + nt * 16 + l16] = v;
        }
      }
  }
}

extern "C" void kernel_launch(void* const* d_in, const int* in_sizes, int n_in,
                              void* d_out, int out_size, void* d_ws, size_t ws_size,
                              hipStream_t stream) {
  const float* hs   = (const float*)d_in[0];
  const float* mask = (const float*)d_in[1];
  const float* Wq   = (const float*)d_in[2];
  const float* bq   = (const float*)d_in[3];
  const float* Wk   = (const float*)d_in[4];
  const float* bk   = (const float*)d_in[5];
  const float* Wv   = (const float*)d_in[6];
  const float* bv   = (const float*)d_in[7];
  const float* Wo   = (const float*)d_in[8];
  const float* bo   = (const float*)d_in[9];
  float* out = (float*)d_out;
  char* ws = (char*)d_ws;
  const size_t MiB = 1048576;

  // Workspace map (peak 44 MiB, all lifetimes checked):
  unsigned short* Wo_hi   = (unsigned short*)(ws);
  unsigned short* Wo_lo   = (unsigned short*)(ws + 2 * MiB);
  unsigned short* hs_pk   = (unsigned short*)(ws + 4 * MiB);
  unsigned short* Kpk     = (unsigned short*)(ws + 4 * MiB);
  unsigned short* Vpk     = (unsigned short*)(ws + 6 * MiB);
  float*          attn_o  = (float*)(ws + 8 * MiB);
  unsigned short* Wqkv_hi = (unsigned short*)(ws + 12 * MiB);
  float*          bias_c  = (float*)(ws + 15 * MiB);
  unsigned short* qkvproj = (unsigned short*)(ws + 16 * MiB);
  unsigned short* ao_hi   = (unsigned short*)(ws + 24 * MiB);
  unsigned short* Qpk_h   = (unsigned short*)(ws + 28 * MiB);
  unsigned short* ao_lo   = (unsigned short*)(ws + 32 * MiB);
  unsigned short* Qpk_l   = (unsigned short*)(ws + 36 * MiB);

  // --- 1. all input packing + bias concat (one dispatch) ---
  prep_pack_kernel<<<3334, 256, 0, stream>>>(
      hs, Wq, Wk, Wv, Wo, bq, bk, bv, hs_pk, Wqkv_hi, Wo_hi, Wo_lo, bias_c);

  // --- 2. fused QKV projection (bf16 MFMA, 64x128 tile, N=1536) ---
  gemm_pk_kernel<1, true><<<dim3(12, 64), 256, 0, stream>>>(
      hs_pk, nullptr, Wqkv_hi, nullptr, bias_c, qkvproj, 1536);

  // --- 3. rope + rmsnorm -> frag-major packed Q/K/V ---
  rope_norm_kernel<<<dim3(SEQ, BATCH), dim3(1024), 0, stream>>>(
      qkvproj, Qpk_h, Qpk_l, Kpk, Vpk);

  // --- 4. attention: v9 = v6 + counted-vmcnt mask prefetch (T4) ---
  attn_mfma9_kernel<<<dim3(SEQ / 32, NKV, BATCH), dim3(512), 0, stream>>>(
      Qpk_h, Qpk_l, Kpk, Vpk, mask, attn_o);

  // --- 5. O-proj input pack (hi/lo) ---
  pack_a_kernel<true><<<2048, 256, 0, stream>>>(attn_o, ao_hi, ao_lo);

  // --- 6. O projection: 3-chain MFMA GEMM ---
  gemm_pk_kernel<3, false><<<dim3(8, 64), 256, 0, stream>>>(
      ao_hi, ao_lo, Wo_hi, Wo_lo, bo, out, 1024);
}

// Round 11
// 254.048 us; speedup vs baseline: 1.0476x; 1.0476x over previous
//
#include <hip/hip_runtime.h>
#include <cmath>

#define SEQ 2048
#define BATCH 2
#define HID 1024
#define NH 16
#define NKV 4
#define DH 64
#define KVDIM 256
#define K32C 32          // K=1024 -> 32 chunks of 32

typedef __attribute__((ext_vector_type(8))) short bf16x8;
typedef __attribute__((ext_vector_type(4))) float f32x4;

static __device__ __forceinline__ unsigned short f2bf(float x) {
  union { float f; unsigned u; } v; v.f = x;
  unsigned r = v.u + 0x7fffu + ((v.u >> 16) & 1u);  // RNE
  return (unsigned short)(r >> 16);
}
static __device__ __forceinline__ float bf2f(unsigned short h) {
  union { unsigned u; float f; } v; v.u = ((unsigned)h) << 16;
  return v.f;
}
static __device__ __forceinline__ void gl_lds16(const void* g, void* l) {
  __builtin_amdgcn_global_load_lds(
      (const __attribute__((address_space(1))) unsigned int*)g,
      (__attribute__((address_space(3))) unsigned int*)l, 16, 0, 0);
}

// fast sincos: sin/cos(sf*invf) via hardware v_sin/v_cos (revolution domain).
static __device__ __forceinline__ void fast_sincos(
    float sf, float g, float* sn, float* cs) {
  float p = sf * g;
  float pe = fmaf(sf, g, -p);          // exact rounding residual
  float rev = (p - floorf(p)) + pe;
  rev -= floorf(rev);                  // [0,1)
  *sn = __builtin_amdgcn_sinf(rev);    // sin(2*pi*rev)
  *cs = __builtin_amdgcn_cosf(rev);
}

// ---- pack bodies (device funcs used by the prep kernel) --------------------
template<bool HILO>
static __device__ __forceinline__ void pack_a_body(
    const float* __restrict__ A, unsigned short* __restrict__ hi,
    unsigned short* __restrict__ lo, int lbid) {
  int gid = lbid * 256 + threadIdx.x;
  int lane = gid & 63;
  int k32 = (gid >> 6) & 31;
  int m16 = gid >> 11;
  int quad = lane >> 4, l16 = lane & 15;
  const float* src = A + (size_t)(m16 * 16 + l16) * 1024 + k32 * 32 + quad * 8;
  float4 a0 = *(const float4*)src;
  float4 a1 = *(const float4*)(src + 4);
  float v[8] = {a0.x, a0.y, a0.z, a0.w, a1.x, a1.y, a1.z, a1.w};
  unsigned short h[8], l[8];
#pragma unroll
  for (int j = 0; j < 8; ++j) {
    h[j] = f2bf(v[j]);
    if (HILO) l[j] = f2bf(v[j] - bf2f(h[j]));
  }
  *(bf16x8*)(hi + (size_t)gid * 8) = *(bf16x8*)h;
  if (HILO) *(bf16x8*)(lo + (size_t)gid * 8) = *(bf16x8*)l;
}

template<bool HILO>
static __device__ __forceinline__ void pack_b_body(
    const float* __restrict__ W, unsigned short* __restrict__ hi,
    unsigned short* __restrict__ lo, int Nsrc, int lbid) {
  int gid = lbid * 256 + threadIdx.x;
  int lane = gid & 63;
  int k32 = (gid >> 6) & 31;
  int n16 = gid >> 11;
  int quad = lane >> 4, l16 = lane & 15;
  int n = n16 * 16 + l16, k = k32 * 32 + quad * 8;
  unsigned short h[8], l[8];
#pragma unroll
  for (int j = 0; j < 8; ++j) {
    float v = W[(size_t)(k + j) * Nsrc + n];
    h[j] = f2bf(v);
    if (HILO) l[j] = f2bf(v - bf2f(h[j]));
  }
  *(bf16x8*)(hi + (size_t)gid * 8) = *(bf16x8*)h;
  if (HILO) *(bf16x8*)(lo + (size_t)gid * 8) = *(bf16x8*)l;
}

// ---- mega prep kernel: all input packing + bias concat in ONE dispatch -----
__global__ __launch_bounds__(256) void prep_pack_kernel(
    const float* __restrict__ hs, const float* __restrict__ Wq,
    const float* __restrict__ Wk, const float* __restrict__ Wv,
    const float* __restrict__ Wo, const float* __restrict__ bq,
    const float* __restrict__ bk, const float* __restrict__ bv,
    unsigned short* __restrict__ hs_pk, unsigned short* __restrict__ Wqkv_hi,
    unsigned short* __restrict__ Wo_hi, unsigned short* __restrict__ Wo_lo,
    float* __restrict__ bias_c) {
  const int bid = blockIdx.x;
  if (bid < 2048) {
    pack_a_body<false>(hs, hs_pk, nullptr, bid);
  } else if (bid < 2560) {
    pack_b_body<false>(Wq, Wqkv_hi, nullptr, 1024, bid - 2048);
  } else if (bid < 2688) {
    pack_b_body<false>(Wk, Wqkv_hi + (size_t)64 * 2048 * 8, nullptr, 256, bid - 2560);
  } else if (bid < 2816) {
    pack_b_body<false>(Wv, Wqkv_hi + (size_t)80 * 2048 * 8, nullptr, 256, bid - 2688);
  } else if (bid < 3328) {
    pack_b_body<true>(Wo, Wo_hi, Wo_lo, 1024, bid - 2816);
  } else {
    int n = (bid - 3328) * 256 + threadIdx.x;
    if (n < 1536)
      bias_c[n] = (n < 1024) ? bq[n] : (n < 1280 ? bk[n - 1024] : bv[n - 1280]);
  }
}

// ---- packed-input MFMA GEMM, 64x128 tile, 2-barrier (QKV projection) ------
template<int CHAINS, bool OUTBF16>
__global__ __launch_bounds__(256) void gemm_pk_kernel(
    const unsigned short* __restrict__ Ah, const unsigned short* __restrict__ Al,
    const unsigned short* __restrict__ Bh, const unsigned short* __restrict__ Bl,
    const float* __restrict__ bias, void* __restrict__ Cout, int N) {
  constexpr int NCH = (CHAINS == 3) ? 2 : 1;
  __shared__ unsigned short Asm[NCH][4 * 512];
  __shared__ unsigned short Bsm[NCH][8 * 512];
  const int tid = threadIdx.x;
  const int wave = tid >> 6, lane = tid & 63;
  const int wr = wave >> 1, wc = wave & 1;
  const int quad = lane >> 4, l16 = lane & 15;
  const size_t abase = ((size_t)(blockIdx.y * 4 + wave) * K32C) * 64 + lane;
  const size_t bbase0 = ((size_t)(blockIdx.x * 8 + wave) * K32C) * 64 + lane;
  const size_t bbase1 = ((size_t)(blockIdx.x * 8 + wave + 4) * K32C) * 64 + lane;
  f32x4 acc[2][4] = {};
  for (int k32 = 0; k32 < K32C; ++k32) {
    __syncthreads();
    gl_lds16(Ah + (abase + (size_t)k32 * 64) * 8, &Asm[0][wave * 512]);
    gl_lds16(Bh + (bbase0 + (size_t)k32 * 64) * 8, &Bsm[0][wave * 512]);
    gl_lds16(Bh + (bbase1 + (size_t)k32 * 64) * 8, &Bsm[0][(wave + 4) * 512]);
    if (CHAINS == 3) {
      gl_lds16(Al + (abase + (size_t)k32 * 64) * 8, &Asm[1][wave * 512]);
      gl_lds16(Bl + (bbase0 + (size_t)k32 * 64) * 8, &Bsm[1][wave * 512]);
      gl_lds16(Bl + (bbase1 + (size_t)k32 * 64) * 8, &Bsm[1][(wave + 4) * 512]);
    }
    __syncthreads();
    bf16x8 af[2][NCH], bfr[4][NCH];
#pragma unroll
    for (int mt = 0; mt < 2; ++mt)
#pragma unroll
      for (int ch = 0; ch < NCH; ++ch)
        af[mt][ch] = *(const bf16x8*)&Asm[ch][((wr * 2 + mt) * 64 + lane) * 8];
#pragma unroll
    for (int nt = 0; nt < 4; ++nt)
#pragma unroll
      for (int ch = 0; ch < NCH; ++ch)
        bfr[nt][ch] = *(const bf16x8*)&Bsm[ch][((wc * 4 + nt) * 64 + lane) * 8];
#pragma unroll
    for (int mt = 0; mt < 2; ++mt)
#pragma unroll
      for (int nt = 0; nt < 4; ++nt) {
        acc[mt][nt] = __builtin_amdgcn_mfma_f32_16x16x32_bf16(af[mt][0], bfr[nt][0], acc[mt][nt], 0, 0, 0);
        if (CHAINS == 3) {
          acc[mt][nt] = __builtin_amdgcn_mfma_f32_16x16x32_bf16(af[mt][1], bfr[nt][0], acc[mt][nt], 0, 0, 0);
          acc[mt][nt] = __builtin_amdgcn_mfma_f32_16x16x32_bf16(af[mt][0], bfr[nt][1], acc[mt][nt], 0, 0, 0);
        }
      }
  }
  const int n0 = blockIdx.x * 128 + wc * 64;
  const int m0 = blockIdx.y * 64 + wr * 32;
#pragma unroll
  for (int mt = 0; mt < 2; ++mt)
#pragma unroll
    for (int nt = 0; nt < 4; ++nt)
#pragma unroll
      for (int r = 0; r < 4; ++r) {
        int gm = m0 + mt * 16 + quad * 4 + r;
        int n = n0 + nt * 16 + l16;
        float v = acc[mt][nt][r] + bias[n];
        if (OUTBF16)
          ((unsigned short*)Cout)[(size_t)gm * N + n] = f2bf(v);
        else
          ((float*)Cout)[(size_t)gm * N + n] = v;
      }
}

// ---- O-projection GEMM with FUSED A-pack (replaces pack_a<true> + CH3 gemm)
// A is read as fp32 attn_o and converted to hi/lo bf16 in the staging phase:
// each wave register-prefetches its 8 A-floats for step k+1 BEFORE the
// compute phase (the load drains at the same barrier that drains the B
// gl_lds -> no new serial stall), then converts (~30 VALU) and ds_writes
// after the next first-barrier. LDS layout and numerics bit-identical to
// pack_a<true>. Saves the 33.6MB pack round-trip + one dispatch.
__global__ __launch_bounds__(256) void gemm_o_fused_kernel(
    const float* __restrict__ Afp, const unsigned short* __restrict__ Bh,
    const unsigned short* __restrict__ Bl, const float* __restrict__ bias,
    float* __restrict__ Cout) {
  __shared__ unsigned short Asm[2][4 * 512];
  __shared__ unsigned short Bsm[2][8 * 512];
  const int tid = threadIdx.x;
  const int wave = tid >> 6, lane = tid & 63;
  const int wr = wave >> 1, wc = wave & 1;
  const int quad = lane >> 4, l16 = lane & 15;
  const int m16 = blockIdx.y * 4 + wave;
  const float* asrc = Afp + (size_t)(m16 * 16 + l16) * 1024 + quad * 8;
  const size_t bbase0 = ((size_t)(blockIdx.x * 8 + wave) * K32C) * 64 + lane;
  const size_t bbase1 = ((size_t)(blockIdx.x * 8 + wave + 4) * K32C) * 64 + lane;
  f32x4 acc[2][4] = {};
  // prologue: A regs for k32=0
  float4 a0 = *(const float4*)(asrc);
  float4 a1 = *(const float4*)(asrc + 4);
  for (int k32 = 0; k32 < K32C; ++k32) {
    __syncthreads();
    {  // convert prefetched A -> hi/lo, stage to LDS (bit-identical to pack_a)
      float v[8] = {a0.x, a0.y, a0.z, a0.w, a1.x, a1.y, a1.z, a1.w};
      unsigned short h[8], l[8];
#pragma unroll
      for (int j = 0; j < 8; ++j) {
        h[j] = f2bf(v[j]);
        l[j] = f2bf(v[j] - bf2f(h[j]));
      }
      *(bf16x8*)&Asm[0][wave * 512 + lane * 8] = *(bf16x8*)h;
      *(bf16x8*)&Asm[1][wave * 512 + lane * 8] = *(bf16x8*)l;
    }
    gl_lds16(Bh + (bbase0 + (size_t)k32 * 64) * 8, &Bsm[0][wave * 512]);
    gl_lds16(Bh + (bbase1 + (size_t)k32 * 64) * 8, &Bsm[0][(wave + 4) * 512]);
    gl_lds16(Bl + (bbase0 + (size_t)k32 * 64) * 8, &Bsm[1][wave * 512]);
    gl_lds16(Bl + (bbase1 + (size_t)k32 * 64) * 8, &Bsm[1][(wave + 4) * 512]);
    if (k32 + 1 < K32C) {  // register-prefetch A for next step
      a0 = *(const float4*)(asrc + (k32 + 1) * 32);
      a1 = *(const float4*)(asrc + (k32 + 1) * 32 + 4);
    }
    __syncthreads();
    bf16x8 af[2][2], bfr[4][2];
#pragma unroll
    for (int mt = 0; mt < 2; ++mt)
#pragma unroll
      for (int ch = 0; ch < 2; ++ch)
        af[mt][ch] = *(const bf16x8*)&Asm[ch][((wr * 2 + mt) * 64 + lane) * 8];
#pragma unroll
    for (int nt = 0; nt < 4; ++nt)
#pragma unroll
      for (int ch = 0; ch < 2; ++ch)
        bfr[nt][ch] = *(const bf16x8*)&Bsm[ch][((wc * 4 + nt) * 64 + lane) * 8];
#pragma unroll
    for (int mt = 0; mt < 2; ++mt)
#pragma unroll
      for (int nt = 0; nt < 4; ++nt) {
        acc[mt][nt] = __builtin_amdgcn_mfma_f32_16x16x32_bf16(af[mt][0], bfr[nt][0], acc[mt][nt], 0, 0, 0);
        acc[mt][nt] = __builtin_amdgcn_mfma_f32_16x16x32_bf16(af[mt][1], bfr[nt][0], acc[mt][nt], 0, 0, 0);
        acc[mt][nt] = __builtin_amdgcn_mfma_f32_16x16x32_bf16(af[mt][0], bfr[nt][1], acc[mt][nt], 0, 0, 0);
      }
  }
  const int n0 = blockIdx.x * 128 + wc * 64;
  const int m0 = blockIdx.y * 64 + wr * 32;
#pragma unroll
  for (int mt = 0; mt < 2; ++mt)
#pragma unroll
    for (int nt = 0; nt < 4; ++nt)
#pragma unroll
      for (int r = 0; r < 4; ++r) {
        int gm = m0 + mt * 16 + quad * 4 + r;
        int n = n0 + nt * 16 + l16;
        Cout[(size_t)gm * 1024 + n] = acc[mt][nt][r] + bias[n];
      }
}

// ---- merged RoPE+rmsnorm (fast HW trig) ------------------------------------
__global__ __launch_bounds__(1024) void rope_norm_kernel(
    const unsigned short* __restrict__ qkv, unsigned short* __restrict__ Qh,
    unsigned short* __restrict__ Ql, unsigned short* __restrict__ Kpk,
    unsigned short* __restrict__ Vpk) {
  const int s = blockIdx.x, b = blockIdx.y;
  const int t = threadIdx.x;
  const unsigned short* row = qkv + ((size_t)b * SEQ + s) * 1536;
  const float INV2PI = 0.15915494309189535f;
  {  // ---- Q ----
    const int j = t & 511;
    float invf = __builtin_amdgcn_exp2f((float)j * (-13.287712379549449f / 512.0f));
    float c, sn;
    fast_sincos((float)s, invf * INV2PI, &sn, &c);
    float x1 = bf2f(row[j]), x2 = bf2f(row[j + 512]);
    float val = (t < 512) ? (x1 * c - x2 * sn) : (x2 * c + x1 * sn);
    float ss = val * val;
#pragma unroll
    for (int off = 1; off < 64; off <<= 1) ss += __shfl_xor(ss, off);
    float rn = rsqrtf(ss * (1.0f / 64.0f) + 1.1920929e-07f);
    float v = val * rn;
    unsigned short hi = f2bf(v);
    unsigned short lo = f2bf(v - bf2f(hi));
    int h = t >> 6, d = t & 63;
    size_t o = (size_t)(b * NH + h) * 131072 +
               ((((size_t)(s >> 4) * 2 + (d >> 5)) * 64) + ((d >> 3) & 3) * 16 + (s & 15)) * 8 + (d & 7);
    Qh[o] = hi;
    Ql[o] = lo;
  }
  if (t < 256) {  // ---- K ----
    const int j = t & 127;
    float invf = __builtin_amdgcn_exp2f((float)j * (-13.287712379549449f / 128.0f));
    float c, sn;
    fast_sincos((float)s, invf * INV2PI, &sn, &c);
    float x1 = bf2f(row[1024 + j]), x2 = bf2f(row[1024 + 128 + j]);
    float val = (t < 128) ? (x1 * c - x2 * sn) : (x2 * c + x1 * sn);
    float ss = val * val;
#pragma unroll
    for (int off = 1; off < 64; off <<= 1) ss += __shfl_xor(ss, off);
    float rn = rsqrtf(ss * (1.0f / 64.0f) + 1.1920929e-07f);
    float kv = val * rn;
    int h = t >> 6, d = t & 63;
    size_t ko = (size_t)(b * NKV + h) * 131072 +
                ((((size_t)(s >> 4) * 2 + (d >> 5)) * 64) + ((d >> 3) & 3) * 16 + (s & 15)) * 8 + (d & 7);
    Kpk[ko] = f2bf(kv);
  } else if (t < 512) {  // ---- V copy ----
    const int tv = t - 256;
    int h = tv >> 6, d = tv & 63;
    size_t vo = (size_t)(b * NKV + h) * 131072 +
                ((((size_t)(d >> 4) * 64 + (s >> 5)) * 64) + ((s >> 3) & 3) * 16 + (d & 15)) * 8 + (s & 7);
    Vpk[vo] = row[1280 + tv];
  }
}

// ------------------------- MFMA attention v6 (validated best, verbatim) ----
// Post-mortem r10: counted-vmcnt + sched_barrier(0) regressed (82->96us):
// sched_barrier pins the scheduler 32x (m141 lesson) and the asm "memory"
// clobber forces addressing reloads. v6's plain __syncthreads beats all four
// attempted replacements (fused-pack, barrier-free, mask-regs, counted
// vmcnt). Do not touch.
__global__ __launch_bounds__(512, 4) void attn_mfma6_kernel(
    const unsigned short* __restrict__ Qh, const unsigned short* __restrict__ Ql,
    const unsigned short* __restrict__ Kpk, const unsigned short* __restrict__ Vpk,
    const float* __restrict__ mask, float* __restrict__ attn_o) {
  __shared__ __align__(16) char smem[67584];
  unsigned short* Kb = (unsigned short*)smem;            // 16384 B
  unsigned short* Vb = (unsigned short*)(smem + 16384);  // 16384 B
  float*          Msk = (float*)(smem + 32768);          // 16384 B
  unsigned short* Ps = (unsigned short*)(smem + 49152);  // 18432 B

  const int b = blockIdx.z, kvh = blockIdx.y;
  const int q0 = blockIdx.x * 32;
  const int tid = threadIdx.x, wave = tid >> 6, lane = tid & 63;
  const int jh = wave >> 2, w4 = wave & 3;
  const int quad = lane >> 4, l16 = lane & 15;
  const int h = kvh * 4 + w4;

  bf16x8 qh[2][2], ql[2][2];
  {
    const unsigned short* Qb_h = Qh + (size_t)(b * NH + h) * 131072;
    const unsigned short* Qb_l = Ql + (size_t)(b * NH + h) * 131072;
#pragma unroll
    for (int mt = 0; mt < 2; ++mt)
#pragma unroll
      for (int kf = 0; kf < 2; ++kf) {
        size_t o = ((((size_t)(q0 >> 4) + mt) * 2 + kf) * 64 + lane) * 8;
        qh[mt][kf] = *(const bf16x8*)(Qb_h + o);
        ql[mt][kf] = *(const bf16x8*)(Qb_l + o);
      }
  }

  const unsigned short* Kbase = Kpk + (size_t)(b * NKV + kvh) * 131072;
  const unsigned short* Vbase = Vpk + (size_t)(b * NKV + kvh) * 131072;

  const float* mbase = mask + ((size_t)b * SEQ + q0) * SEQ;
  const int srow = w4 * 8 + (lane >> 3);
  const int ssw = ((srow >> 2) & 1) << 4;
  const float* msrc0 = mbase + (size_t)srow * SEQ + (((lane & 7) * 4) ^ ssw);

  bf16x8 ones;
#pragma unroll
  for (int i = 0; i < 8; ++i) ones[i] = (short)0x3F80;  // bf16 1.0

  f32x4 O[2][4] = {};
  f32x4 lAcc[2] = {};

  auto stage = [&](int buf, int jc) {
    const int j0 = jh * (SEQ / 2) + jc * 32;
    gl_lds16(Kbase + ((((size_t)(j0 >> 4) + (w4 >> 1)) * 2 + (w4 & 1)) * 64 + lane) * 8,
             Kb + (buf * 2 + jh) * 2048 + w4 * 512);
    gl_lds16(Vbase + (((size_t)w4 * 64 + (j0 >> 5)) * 64 + lane) * 8,
             Vb + (buf * 2 + jh) * 2048 + w4 * 512);
    gl_lds16(msrc0 + j0, Msk + (buf * 2 + jh) * 1024 + w4 * 256);
  };

  stage(0, 0);
  for (int jc = 0; jc < 32; ++jc) {
    const int cur = jc & 1;
    __syncthreads();  // drains prefetch issued last iter (overlapped)
    if (jc < 31) stage(cur ^ 1, jc + 1);

    bf16x8 kbf[2][2], vbf[4];
#pragma unroll
    for (int nt = 0; nt < 2; ++nt)
#pragma unroll
      for (int kf = 0; kf < 2; ++kf)
        kbf[nt][kf] = *(const bf16x8*)&Kb[(cur * 2 + jh) * 2048 + ((nt * 2 + kf) * 64 + lane) * 8];
#pragma unroll
    for (int d16 = 0; d16 < 4; ++d16)
      vbf[d16] = *(const bf16x8*)&Vb[(cur * 2 + jh) * 2048 + (d16 * 64 + lane) * 8];

    bf16x8 pa[2];
#pragma unroll
    for (int mt = 0; mt < 2; ++mt) {
#pragma unroll
      for (int nt = 0; nt < 2; ++nt) {
        f32x4 C = {};
        C = __builtin_amdgcn_mfma_f32_16x16x32_bf16(qh[mt][0], kbf[nt][0], C, 0, 0, 0);
        C = __builtin_amdgcn_mfma_f32_16x16x32_bf16(qh[mt][1], kbf[nt][1], C, 0, 0, 0);
        C = __builtin_amdgcn_mfma_f32_16x16x32_bf16(ql[mt][0], kbf[nt][0], C, 0, 0, 0);
        C = __builtin_amdgcn_mfma_f32_16x16x32_bf16(ql[mt][1], kbf[nt][1], C, 0, 0, 0);
#pragma unroll
        for (int r = 0; r < 4; ++r) {
          int row16 = quad * 4 + r;
          float m = Msk[(cur * 2 + jh) * 1024 + (mt * 16 + row16) * 32 +
                        ((nt * 16 + l16) ^ ((quad & 1) << 4))];
          float p = __builtin_amdgcn_exp2f(
              fmaf(C[r], 0.18033688f, fmaf(m, 1.44269504f, -11.54156033f)));
          union { float f; unsigned u; } pu; pu.f = p;
          Ps[wave * 1152 + row16 * 72 + nt * 16 + l16] =
              (unsigned short)((pu.u + 0x8000u) >> 16);
        }
      }
      pa[mt] = *(const bf16x8*)&Ps[wave * 1152 + l16 * 72 + quad * 8];
    }
#pragma unroll
    for (int mt = 0; mt < 2; ++mt) {
      lAcc[mt] = __builtin_amdgcn_mfma_f32_16x16x32_bf16(pa[mt], ones, lAcc[mt], 0, 0, 0);
#pragma unroll
      for (int nt = 0; nt < 4; ++nt)
        O[mt][nt] = __builtin_amdgcn_mfma_f32_16x16x32_bf16(pa[mt], vbf[nt], O[mt][nt], 0, 0, 0);
    }
  }

  // ---- epilogue: combine jh halves via LDS, normalize, plain stores ----
  __syncthreads();  // all waves done with Kb/Vb/Msk; safe to alias
  float* Oex = (float*)smem;             // [4][32][68] = 34816 B
  float* lex = (float*)(smem + 34816);   // [128] floats
  if (jh == 1) {
#pragma unroll
    for (int mt = 0; mt < 2; ++mt)
#pragma unroll
      for (int r = 0; r < 4; ++r) {
        int row = mt * 16 + quad * 4 + r;
#pragma unroll
        for (int nt = 0; nt < 4; ++nt)
          Oex[((size_t)w4 * 32 + row) * 68 + nt * 16 + l16] = O[mt][nt][r];
        if (l16 == 0) lex[w4 * 32 + row] = lAcc[mt][r];
      }
  }
  __syncthreads();
  if (jh == 0) {
    float* po = attn_o + ((size_t)b * SEQ + q0) * HID + h * DH;
#pragma unroll
    for (int mt = 0; mt < 2; ++mt)
#pragma unroll
      for (int r = 0; r < 4; ++r) {
        int row = mt * 16 + quad * 4 + r;
        float inv = 1.0f / (lAcc[mt][r] + lex[w4 * 32 + row]);
#pragma unroll
        for (int nt = 0; nt < 4; ++nt) {
          float v = (O[mt][nt][r] + Oex[((size_t)w4 * 32 + row) * 68 + nt * 16 + l16]) * inv;
          po[(size_t)row * HID + nt * 16 + l16] = v;
        }
      }
  }
}

extern "C" void kernel_launch(void* const* d_in, const int* in_sizes, int n_in,
                              void* d_out, int out_size, void* d_ws, size_t ws_size,
                              hipStream_t stream) {
  const float* hs   = (const float*)d_in[0];
  const float* mask = (const float*)d_in[1];
  const float* Wq   = (const float*)d_in[2];
  const float* bq   = (const float*)d_in[3];
  const float* Wk   = (const float*)d_in[4];
  const float* bk   = (const float*)d_in[5];
  const float* Wv   = (const float*)d_in[6];
  const float* bv   = (const float*)d_in[7];
  const float* Wo   = (const float*)d_in[8];
  const float* bo   = (const float*)d_in[9];
  float* out = (float*)d_out;
  char* ws = (char*)d_ws;
  const size_t MiB = 1048576;

  // Workspace map (peak 44 MiB, all lifetimes checked):
  unsigned short* Wo_hi   = (unsigned short*)(ws);
  unsigned short* Wo_lo   = (unsigned short*)(ws + 2 * MiB);
  unsigned short* hs_pk   = (unsigned short*)(ws + 4 * MiB);
  unsigned short* Kpk     = (unsigned short*)(ws + 4 * MiB);
  unsigned short* Vpk     = (unsigned short*)(ws + 6 * MiB);
  float*          attn_o  = (float*)(ws + 8 * MiB);
  unsigned short* Wqkv_hi = (unsigned short*)(ws + 12 * MiB);
  float*          bias_c  = (float*)(ws + 15 * MiB);
  unsigned short* qkvproj = (unsigned short*)(ws + 16 * MiB);
  unsigned short* Qpk_h   = (unsigned short*)(ws + 28 * MiB);
  unsigned short* Qpk_l   = (unsigned short*)(ws + 36 * MiB);

  // --- 1. all input packing + bias concat (one dispatch) ---
  prep_pack_kernel<<<3334, 256, 0, stream>>>(
      hs, Wq, Wk, Wv, Wo, bq, bk, bv, hs_pk, Wqkv_hi, Wo_hi, Wo_lo, bias_c);

  // --- 2. fused QKV projection (bf16 MFMA, 64x128 tile, N=1536) ---
  gemm_pk_kernel<1, true><<<dim3(12, 64), 256, 0, stream>>>(
      hs_pk, nullptr, Wqkv_hi, nullptr, bias_c, qkvproj, 1536);

  // --- 3. rope + rmsnorm -> frag-major packed Q/K/V ---
  rope_norm_kernel<<<dim3(SEQ, BATCH), dim3(1024), 0, stream>>>(
      qkvproj, Qpk_h, Qpk_l, Kpk, Vpk);

  // --- 4. attention: v6 (validated best, verbatim) ---
  attn_mfma6_kernel<<<dim3(SEQ / 32, NKV, BATCH), dim3(512), 0, stream>>>(
      Qpk_h, Qpk_l, Kpk, Vpk, mask, attn_o);

  // --- 5. O projection with fused A-pack (reads fp32 attn_o directly) ---
  gemm_o_fused_kernel<<<dim3(8, 64), 256, 0, stream>>>(
      attn_o, Wo_hi, Wo_lo, bo, out);
}